// Round 2
// baseline (2207.932 us; speedup 1.0000x reference)
//
#include <hip/hip_runtime.h>

namespace {
constexpr int NZ = 256, NX = 256, NT = 256, NR = 128, B = 4;
constexpr int ROWS = 4;                  // rows owned per block
constexpr int BPS = NZ / ROWS;           // z-blocks per shot = 64
constexpr int NB  = B * BPS;             // 256 blocks total
constexpr float DT = 1e-3f, DH = 10.0f, OMEGA = 10.0f;
constexpr float TS  = 1.0f / OMEGA;              // tau_sigma
constexpr float CAv = 1.0f - DT / (2.0f * TS);   // 0.995
constexpr float CBv = 1.0f + DT / (2.0f * TS);   // 1.005
constexpr float CA  = CAv / CBv;
}

// Persistent viscoacoustic FDTD. Each block owns ROWS z-rows of one shot and
// keeps p/vx/vz/r + coefficients in LDS for all NT steps. Per step, only the
// two boundary p-rows are exchanged with z-neighbors through a parity
// double-buffered global halo, ordered by per-block step-counter flags
// (agent-scope release/acquire — correct across non-coherent XCD L2s).
//
// Race-freedom sketch:
//  * Block zb starts step t only after flags[zb±1] >= t, i.e. both neighbors
//    published p^t boundary rows. Skew between neighbors is therefore <= 1.
//  * Publish of p^{t+2} lands in halo[(t+2)&1] == halo[t&1], whose previous
//    content (p^t) was consumed by the neighbor BEFORE it raised flag = t+1 —
//    and flag = t+1 is required before we may even start step t+1. No WAR.
//  * The redundant vz row z0+ROWS is recomputed locally from identical inputs
//    each step (both copies start at 0) — bit-identical, no vz exchange.
__global__ __launch_bounds__(256, 1) void wave_persistent(
    const float* __restrict__ wav,   // x: [B, NT, 1]
    const float* __restrict__ vp, const float* __restrict__ rho,
    const float* __restrict__ Q,
    const int* __restrict__ src_z, const int* __restrict__ src_x,
    const int* __restrict__ rec_x, const int* __restrict__ rec_z,
    float* __restrict__ out,         // [NT, NR, B]
    float* haloT, float* haloB,      // each [2][NB][NX]
    int* flags)                      // [NB], zeroed before launch
{
  const int x   = threadIdx.x;       // column 0..255
  const int bid = blockIdx.x;
  const int b   = bid / BPS;
  const int zb  = bid % BPS;
  const int z0  = zb * ROWS;

  __shared__ float p_s [ROWS + 2][NX + 1];  // rows z0-1 .. z0+ROWS; col ghost at 0
  __shared__ float vx_s[ROWS][NX + 1];      // col ghost at NX (dxf pad)
  __shared__ float vz_s[ROWS + 1][NX];      // incl. redundant row z0+ROWS
  __shared__ float r_s [ROWS][NX];
  __shared__ float a1_s[ROWS + 1][NX];      // DT/(rho*DH), incl. redundant row
  __shared__ float b2_s[ROWS][NX];
  __shared__ float b3_s[ROWS][NX];
  __shared__ float wav_s[NT];
  __shared__ int   rx_s[NR];

  // ---- init: zero state, compute coefficients, stage wavelet/receivers ----
  #pragma unroll
  for (int k = 0; k < ROWS + 2; ++k) p_s[k][x + 1] = 0.0f;
  if (x < ROWS + 2) p_s[x][0] = 0.0f;               // p[z][-1] ghost (dxb pad)
  #pragma unroll
  for (int i = 0; i < ROWS; ++i) { vx_s[i][x] = 0.0f; r_s[i][x] = 0.0f; }
  if (x < ROWS) vx_s[x][NX] = 0.0f;                 // vx[z][NX] ghost (dxf pad)
  #pragma unroll
  for (int i = 0; i < ROWS + 1; ++i) vz_s[i][x] = 0.0f;
  #pragma unroll
  for (int i = 0; i < ROWS; ++i) {
    int gi = (z0 + i) * NX + x;
    float v = vp[gi], rh = rho[gi], q = Q[gi];
    float kappa = rh * v * v, tau = 1.0f / q;
    a1_s[i][x] = DT / (rh * DH);
    b2_s[i][x] = DT * kappa * tau / (TS * CBv * DH);
    b3_s[i][x] = DT * kappa * (1.0f + tau) / DH;
  }
  { int z = z0 + ROWS;                              // redundant-row coefficient
    a1_s[ROWS][x] = (z < NZ) ? DT / (rho[z * NX + x] * DH) : 0.0f; }
  wav_s[x] = wav[b * NT + x];
  if (x < NR) rx_s[x] = rec_x[x];
  const int sz = src_z[b], sx = src_x[b];
  const int rz = rec_z[0];
  const bool rec_owner = (rz >= z0 && rz < z0 + ROWS);
  __syncthreads();

  for (int t = 0; t < NT; ++t) {
    // ---- acquire neighbors' p^t boundary rows (t=0: all-zero init state) ----
    if (t > 0) {
      if (x == 0 && zb > 0) {
        int g = 0;
        while (__hip_atomic_load(&flags[bid - 1], __ATOMIC_ACQUIRE,
                                 __HIP_MEMORY_SCOPE_AGENT) < t && ++g < (1 << 28)) {}
      }
      if (x == 1 && zb < BPS - 1) {
        int g = 0;
        while (__hip_atomic_load(&flags[bid + 1], __ATOMIC_ACQUIRE,
                                 __HIP_MEMORY_SCOPE_AGENT) < t && ++g < (1 << 28)) {}
      }
      __syncthreads();
      const size_t par = (size_t)(t & 1) * NB * NX;
      p_s[0][x + 1] = (zb > 0)
          ? __hip_atomic_load(&haloB[par + (size_t)(bid - 1) * NX + x],
                              __ATOMIC_RELAXED, __HIP_MEMORY_SCOPE_AGENT)
          : 0.0f;
      p_s[ROWS + 1][x + 1] = (zb < BPS - 1)
          ? __hip_atomic_load(&haloT[par + (size_t)(bid + 1) * NX + x],
                              __ATOMIC_RELAXED, __HIP_MEMORY_SCOPE_AGENT)
          : 0.0f;
      // halo rows are consumed same-column only -> no extra barrier needed
    }

    // ---- velocity update (reads p_s; writes own column of vx_s/vz_s) ----
    #pragma unroll
    for (int i = 0; i < ROWS; ++i) {
      float a1 = a1_s[i][x];
      vx_s[i][x] -= a1 * (p_s[i + 1][x + 1] - p_s[i + 1][x]);
      vz_s[i][x] -= a1 * (p_s[i + 1][x + 1] - p_s[i][x + 1]);
    }
    // redundant vz row z0+ROWS (bit-identical to next block's own row)
    vz_s[ROWS][x] -= a1_s[ROWS][x] * (p_s[ROWS + 1][x + 1] - p_s[ROWS][x + 1]);
    __syncthreads();

    // ---- memory variable + pressure update (own column) ----
    const float xi = wav_s[t];
    #pragma unroll
    for (int i = 0; i < ROWS; ++i) {
      float divr = (vx_s[i][x + 1] - vx_s[i][x]) + (vz_s[i + 1][x] - vz_s[i][x]);
      float rn = CA * r_s[i][x] - b2_s[i][x] * divr;
      r_s[i][x] = rn;
      float pn = p_s[i + 1][x + 1] - b3_s[i][x] * divr + DT * rn;
      if (z0 + i == sz && x == sx) pn += xi;        // source injection
      p_s[i + 1][x + 1] = pn;
    }

    // ---- publish p^{t+1} boundary rows (own column; parity buffer t+1) ----
    {
      const size_t par = (size_t)((t + 1) & 1) * NB * NX;
      if (zb > 0)
        __hip_atomic_store(&haloT[par + (size_t)bid * NX + x], p_s[1][x + 1],
                           __ATOMIC_RELAXED, __HIP_MEMORY_SCOPE_AGENT);
      if (zb < BPS - 1)
        __hip_atomic_store(&haloB[par + (size_t)bid * NX + x], p_s[ROWS][x + 1],
                           __ATOMIC_RELAXED, __HIP_MEMORY_SCOPE_AGENT);
    }
    __syncthreads();   // drains vmcnt -> halo stores device-visible; also
                       // orders p_s writes before cross-column readout below
    if (x == 0)
      __hip_atomic_store(&flags[bid], t + 1, __ATOMIC_RELEASE,
                         __HIP_MEMORY_SCOPE_AGENT);
    if (rec_owner && x < NR)
      out[(size_t)t * NR * B + (size_t)x * B + b] = p_s[rz - z0 + 1][rx_s[x] + 1];
  }
}

extern "C" void kernel_launch(void* const* d_in, const int* in_sizes, int n_in,
                              void* d_out, int out_size, void* d_ws, size_t ws_size,
                              hipStream_t stream) {
  const float* xw  = (const float*)d_in[0];
  const float* vp  = (const float*)d_in[1];
  const float* rho = (const float*)d_in[2];
  const float* Q   = (const float*)d_in[3];
  const int* src_z = (const int*)d_in[4];
  const int* src_x = (const int*)d_in[5];
  const int* rec_x = (const int*)d_in[6];
  const int* rec_z = (const int*)d_in[7];
  float* out = (float*)d_out;

  float* haloT = (float*)d_ws;                       // [2][NB][NX]
  float* haloB = haloT + (size_t)2 * NB * NX;        // [2][NB][NX]
  int*   flags = (int*)(haloB + (size_t)2 * NB * NX);

  hipMemsetAsync(flags, 0, NB * sizeof(int), stream);
  wave_persistent<<<NB, 256, 0, stream>>>(xw, vp, rho, Q, src_z, src_x,
                                          rec_x, rec_z, out, haloT, haloB, flags);
}

// Round 3
// 813.465 us; speedup vs baseline: 2.7142x; 2.7142x over previous
//
#include <hip/hip_runtime.h>

namespace {
constexpr int NZ = 256, NX = 256, NT = 256, NR = 128, B = 4;
constexpr int K = 8;                     // fused time steps per launch
constexpr int OROWS = 4;                 // rows owned (written back) per block
constexpr int IROWS = OROWS + 2 * K;     // 20 rows loaded (halo for K-step cone)
constexpr int ZB = NZ / OROWS;           // 64 z-blocks per shot
constexpr int NBLK = B * ZB;             // 256 blocks
constexpr int NL = NT / K;               // 32 launches
constexpr float DT = 1e-3f, DH = 10.0f, OMEGA = 10.0f;
constexpr float TS  = 1.0f / OMEGA;
constexpr float CBv = 1.0f + DT / (2.0f * TS);
constexpr float CA  = (1.0f - DT / (2.0f * TS)) / CBv;
}

// a1 = DT/(rho*DH); b2 = DT*kappa*tau/(TS*cb*DH); b3 = DT*kappa*(1+tau)/DH
__global__ void coef_kernel(const float* __restrict__ vp, const float* __restrict__ rho,
                            const float* __restrict__ Q,
                            float* __restrict__ a1, float* __restrict__ b2,
                            float* __restrict__ b3) {
  int i = blockIdx.x * blockDim.x + threadIdx.x;
  if (i >= NZ * NX) return;
  float v = vp[i], rh = rho[i], q = Q[i];
  float kappa = rh * v * v, tau = 1.0f / q;
  a1[i] = DT / (rh * DH);
  b2[i] = DT * kappa * tau / (TS * CBv * DH);
  b3[i] = DT * kappa * (1.0f + tau) / DH;
}

// Time-skewed block: loads IROWS rows of (p,vx,vz,r), advances K steps with
// redundant halo compute (validity cone shrinks 1 row/side/step at interior
// edges; domain edges enforced by zeroed out-of-domain coefficients, which
// keep zero state exactly zero = correct pad), stores OROWS owned rows.
// vz/r are column-local -> registers. p/vx need x-neighbors -> LDS mirrors
// (+ register copies so each row needs only ~4 LDS ops per substep).
__global__ __launch_bounds__(256, 1) void step_fused(
    const float* __restrict__ Pin,  float* __restrict__ Pout,
    const float* __restrict__ VXin, float* __restrict__ VXout,
    const float* __restrict__ VZin, float* __restrict__ VZout,
    const float* __restrict__ Rin,  float* __restrict__ Rout,
    const float* __restrict__ a1g, const float* __restrict__ b2g,
    const float* __restrict__ b3g, const float* __restrict__ wav,
    const int* __restrict__ src_z, const int* __restrict__ src_x,
    const int* __restrict__ rec_x, const int* __restrict__ rec_z,
    float* __restrict__ out, int t0)
{
  const int x   = threadIdx.x;           // column 0..255
  const int bid = blockIdx.x;
  const int b   = bid / ZB, zb = bid % ZB;
  const int z0  = zb * OROWS;
  const int zi0 = z0 - K;                // first loaded global row (may be <0)
  const size_t base = (size_t)b * NZ * NX;

  __shared__ float p_s [IROWS + 2][NX + 1];  // [j+1][x+1]; col 0 ghost (dxb pad)
  __shared__ float vx_s[IROWS][NX + 1];      // col NX ghost (dxf pad)
  __shared__ int   rx_s[NR];

  float pr[IROWS], vxr[IROWS], vz[IROWS], rr[IROWS];
  float a1[IROWS], b2[IROWS], b3[IROWS], w[K];

  #pragma unroll
  for (int j = 0; j < IROWS; ++j) {
    int g = zi0 + j;
    bool in = (unsigned)g < (unsigned)NZ;
    size_t gi = base + (size_t)g * NX + x;
    size_t ci = (size_t)g * NX + x;
    pr[j]  = in ? Pin[gi]  : 0.0f;
    vxr[j] = in ? VXin[gi] : 0.0f;
    vz[j]  = in ? VZin[gi] : 0.0f;
    rr[j]  = in ? Rin[gi]  : 0.0f;
    a1[j]  = in ? a1g[ci]  : 0.0f;       // zero coef outside domain:
    b2[j]  = in ? b2g[ci]  : 0.0f;       // zero state stays exactly zero
    b3[j]  = in ? b3g[ci]  : 0.0f;
    p_s[j + 1][x + 1] = pr[j];
    vx_s[j][x] = vxr[j];
  }
  if (x < IROWS + 2) p_s[x][0] = 0.0f;   // left ghost col (never written)
  p_s[0][x + 1] = 0.0f;                  // row above (only feeds edge-garbage vz)
  p_s[IROWS + 1][x + 1] = 0.0f;
  if (x < IROWS) vx_s[x][NX] = 0.0f;     // right ghost col (never written)
  if (x < NR) rx_s[x] = rec_x[x];
  #pragma unroll
  for (int s = 0; s < K; ++s) w[s] = wav[b * NT + t0 + s];
  const int sz = src_z[b], sx = src_x[b];
  const int rz = rec_z[0];
  const bool owner = (rz >= z0 && rz < z0 + OROWS);  // unique per shot
  const int jr = rz - zi0;
  __syncthreads();

  #pragma unroll
  for (int s = 0; s < K; ++s) {
    // ---- phase A: velocities (reads p_s cross-lane; writes vx_s own col) ----
    float pm = 0.0f;                     // p[row j-1] rolling (j=0: ghost/garbage)
    #pragma unroll
    for (int j = 0; j < IROWS; ++j) {
      float pc = pr[j];
      float pl = p_s[j + 1][x];          // left neighbor column
      float vxn = vxr[j] - a1[j] * (pc - pl);
      vxr[j] = vxn;
      vx_s[j][x] = vxn;
      vz[j] -= a1[j] * (pc - pm);
      pm = pc;
    }
    __syncthreads();
    // ---- phase B: div, memory var, pressure (reads vx_s cross-lane) ----
    #pragma unroll
    for (int j = 0; j < IROWS; ++j) {
      float vxrgt = vx_s[j][x + 1];
      float vznxt = (j + 1 < IROWS) ? vz[j + 1] : 0.0f;  // edge-garbage row only
      float div = (vxrgt - vxr[j]) + (vznxt - vz[j]);
      float rn = CA * rr[j] - b2[j] * div;
      rr[j] = rn;
      float pn = pr[j] - b3[j] * div + DT * rn;
      if (zi0 + j == sz && x == sx) pn += w[s];          // source injection
      pr[j] = pn;
      p_s[j + 1][x + 1] = pn;
    }
    __syncthreads();
    // ---- receiver probe of p^{t+1} (owner block; row rz always valid) ----
    if (owner && x < NR)
      out[(size_t)(t0 + s) * NR * B + (size_t)x * B + b] =
          p_s[jr + 1][rx_s[x] + 1];
    // (next phase A writes only vx_s -> no conflict with this p_s read)
  }

  // ---- store owned rows (valid after exactly K steps) ----
  #pragma unroll
  for (int j = K; j < K + OROWS; ++j) {
    size_t gi = base + (size_t)(zi0 + j) * NX + x;
    Pout[gi]  = pr[j];
    VXout[gi] = vxr[j];
    VZout[gi] = vz[j];
    Rout[gi]  = rr[j];
  }
}

extern "C" void kernel_launch(void* const* d_in, const int* in_sizes, int n_in,
                              void* d_out, int out_size, void* d_ws, size_t ws_size,
                              hipStream_t stream) {
  const float* xw  = (const float*)d_in[0];
  const float* vp  = (const float*)d_in[1];
  const float* rho = (const float*)d_in[2];
  const float* Q   = (const float*)d_in[3];
  const int* src_z = (const int*)d_in[4];
  const int* src_x = (const int*)d_in[5];
  const int* rec_x = (const int*)d_in[6];
  const int* rec_z = (const int*)d_in[7];
  float* out = (float*)d_out;
  float* ws  = (float*)d_ws;

  const size_t S = (size_t)B * NZ * NX;        // 262144 elems per field
  // buffer 0: P,VX,VZ,R contiguous (zeroed each call); buffer 1: same
  float* P[2]  = {ws,         ws + 4 * S};
  float* VX[2] = {ws + S,     ws + 5 * S};
  float* VZ[2] = {ws + 2 * S, ws + 6 * S};
  float* R[2]  = {ws + 3 * S, ws + 7 * S};
  float* a1 = ws + 8 * S;
  float* b2 = a1 + (size_t)NZ * NX;
  float* b3 = b2 + (size_t)NZ * NX;

  hipMemsetAsync(ws, 0, 4 * S * sizeof(float), stream);   // zero initial state
  coef_kernel<<<(NZ * NX + 255) / 256, 256, 0, stream>>>(vp, rho, Q, a1, b2, b3);

  for (int l = 0; l < NL; ++l) {
    int i = l & 1, o = i ^ 1;
    step_fused<<<NBLK, 256, 0, stream>>>(P[i], P[o], VX[i], VX[o],
                                         VZ[i], VZ[o], R[i], R[o],
                                         a1, b2, b3, xw, src_z, src_x,
                                         rec_x, rec_z, out, l * K);
  }
}

// Round 5
// 465.002 us; speedup vs baseline: 4.7482x; 1.7494x over previous
//
#include <hip/hip_runtime.h>

namespace {
constexpr int NZ = 256, NX = 256, NT = 256, NR = 128, B = 4;
constexpr int K = 8;                     // fused time steps per launch
constexpr int OROWS = 4;                 // rows owned (written back) per block
constexpr int IROWS = OROWS + 2 * K;     // 20 rows loaded (halo for K-step cone)
constexpr int NSTRIP = 4;                // z-strips (waves-groups) per block
constexpr int RPT = IROWS / NSTRIP;      // 5 rows per thread
constexpr int ZB = NZ / OROWS;           // 64 z-blocks per shot
constexpr int NBLK = B * ZB;             // 256 blocks
constexpr int NL = NT / K;               // 32 launches
constexpr float DT = 1e-3f, DH = 10.0f, OMEGA = 10.0f;
constexpr float TS  = 1.0f / OMEGA;
constexpr float CBv = 1.0f + DT / (2.0f * TS);
constexpr float CA  = (1.0f - DT / (2.0f * TS)) / CBv;
}

// a1 = DT/(rho*DH); b2 = DT*kappa*tau/(TS*cb*DH); b3 = DT*kappa*(1+tau)/DH
__global__ void coef_kernel(const float* __restrict__ vp, const float* __restrict__ rho,
                            const float* __restrict__ Q,
                            float* __restrict__ a1, float* __restrict__ b2,
                            float* __restrict__ b3) {
  int i = blockIdx.x * blockDim.x + threadIdx.x;
  if (i >= NZ * NX) return;
  float v = vp[i], rh = rho[i], q = Q[i];
  float kappa = rh * v * v, tau = 1.0f / q;
  a1[i] = DT / (rh * DH);
  b2[i] = DT * kappa * tau / (TS * CBv * DH);
  b3[i] = DT * kappa * (1.0f + tau) / DH;
}

// Time-skewed block, 1024 threads = 4 z-strips x 256 columns. Thread (g,x)
// owns window rows [g*5, g*5+5) in registers; p and vx are mirrored in LDS
// for cross-column (x) and cross-strip (z) neighbor access; vz crosses strip
// boundaries via a 1-row-per-strip LDS buffer. Arithmetic identical to the
// round-3 kernel (validity cone + zeroed out-of-domain coefficients).
__global__ __launch_bounds__(1024, 4) void step_fused(
    const float* __restrict__ Pin,  float* __restrict__ Pout,
    const float* __restrict__ VXin, float* __restrict__ VXout,
    const float* __restrict__ VZin, float* __restrict__ VZout,
    const float* __restrict__ Rin,  float* __restrict__ Rout,
    const float* __restrict__ a1g, const float* __restrict__ b2g,
    const float* __restrict__ b3g, const float* __restrict__ wav,
    const int* __restrict__ src_z, const int* __restrict__ src_x,
    const int* __restrict__ rec_x, const int* __restrict__ rec_z,
    float* __restrict__ out, int t0)
{
  const int tid = threadIdx.x;
  const int x   = tid & (NX - 1);        // column 0..255
  const int g   = tid >> 8;              // strip 0..3
  const int j0  = g * RPT;               // first window row of this strip
  const int bid = blockIdx.x;
  const int b   = bid / ZB, zb = bid % ZB;
  const int z0  = zb * OROWS;
  const int zi0 = z0 - K;                // first loaded global row (may be <0)
  const size_t base = (size_t)b * NZ * NX;

  __shared__ float p_s [IROWS + 2][NX + 1];  // [j+1][x+1]; col 0 + rows -1/20 ghosts
  __shared__ float vx_s[IROWS][NX + 1];      // col NX ghost (dxf pad)
  __shared__ float vzb [NSTRIP][NX];         // bottom vz row of each strip
  __shared__ float wav_s[K];
  __shared__ int   rx_s[NR];

  float pr[RPT], vxr[RPT], vz[RPT], rr[RPT], a1[RPT], b2[RPT], b3[RPT];

  #pragma unroll
  for (int jj = 0; jj < RPT; ++jj) {
    int j = j0 + jj, gz = zi0 + j;
    bool in = (unsigned)gz < (unsigned)NZ;
    size_t gi = base + (size_t)gz * NX + x;
    size_t ci = (size_t)gz * NX + x;
    pr[jj]  = in ? Pin[gi]  : 0.0f;
    vxr[jj] = in ? VXin[gi] : 0.0f;
    vz[jj]  = in ? VZin[gi] : 0.0f;
    rr[jj]  = in ? Rin[gi]  : 0.0f;
    a1[jj]  = in ? a1g[ci]  : 0.0f;      // zero coef outside domain:
    b2[jj]  = in ? b2g[ci]  : 0.0f;      // zero state stays exactly zero
    b3[jj]  = in ? b3g[ci]  : 0.0f;
    p_s[j + 1][x + 1] = pr[jj];
    vx_s[j][x] = vxr[jj];
  }
  if (tid < IROWS + 2) p_s[tid][0] = 0.0f;   // left ghost col (never written)
  if (tid < IROWS)     vx_s[tid][NX] = 0.0f; // right ghost col (never written)
  if (g == 0) p_s[0][x + 1] = 0.0f;          // row -1 ghost (feeds edge-garbage vz)
  if (g == 1) p_s[IROWS + 1][x + 1] = 0.0f;  // row 20 ghost (unused, keep defined)
  if (tid < NR) rx_s[tid] = rec_x[tid];
  if (tid < K)  wav_s[tid] = wav[b * NT + t0 + tid];
  const int sz = src_z[b], sx = src_x[b];
  const int rz = rec_z[0];
  const bool owner = (rz >= z0 && rz < z0 + OROWS);   // unique per shot
  const int jr = rz - zi0;
  __syncthreads();

  for (int s = 0; s < K; ++s) {
    // ---- phase A: velocities (reads p_s; writes vx_s / vzb, own column) ----
    #pragma unroll
    for (int jj = 0; jj < RPT; ++jj) {
      int j = j0 + jj;
      float pc = pr[jj];
      float pl = p_s[j + 1][x];                      // left-column neighbor
      float pu = (jj > 0) ? pr[jj - 1] : p_s[j0][x + 1];  // row j-1 (reg or LDS)
      vxr[jj] -= a1[jj] * (pc - pl);
      vx_s[j][x] = vxr[jj];
      vz[jj]  -= a1[jj] * (pc - pu);
    }
    vzb[g][x] = vz[0];
    __syncthreads();

    // ---- phase B: div, memory var, pressure ----
    const float xi = wav_s[s];
    #pragma unroll
    for (int jj = 0; jj < RPT; ++jj) {
      int j = j0 + jj;
      float vxrgt = vx_s[j][x + 1];
      float vznxt = (jj < RPT - 1) ? vz[jj + 1]
                   : ((g < NSTRIP - 1) ? vzb[g + 1][x] : 0.0f);  // edge-garbage row
      float div = (vxrgt - vxr[jj]) + (vznxt - vz[jj]);
      float rn = CA * rr[jj] - b2[jj] * div;
      rr[jj] = rn;
      float pn = pr[jj] - b3[jj] * div + DT * rn;
      if (zi0 + j == sz && x == sx) pn += xi;        // source injection
      pr[jj] = pn;
      p_s[j + 1][x + 1] = pn;
    }
    __syncthreads();

    // ---- receiver probe of p after this step (owner block; row rz valid) ----
    if (owner && tid < NR)
      out[(size_t)(t0 + s) * NR * B + (size_t)tid * B + b] =
          p_s[jr + 1][rx_s[tid] + 1];
    // next phase A writes only vx_s/vzb; next p_s write is behind a barrier
  }

  // ---- store owned rows (valid after exactly K steps) ----
  #pragma unroll
  for (int jj = 0; jj < RPT; ++jj) {
    int j = j0 + jj;
    if (j >= K && j < K + OROWS) {
      size_t gi = base + (size_t)(zi0 + j) * NX + x;
      Pout[gi]  = pr[jj];
      VXout[gi] = vxr[jj];
      VZout[gi] = vz[jj];
      Rout[gi]  = rr[jj];
    }
  }
}

extern "C" void kernel_launch(void* const* d_in, const int* in_sizes, int n_in,
                              void* d_out, int out_size, void* d_ws, size_t ws_size,
                              hipStream_t stream) {
  const float* xw  = (const float*)d_in[0];
  const float* vp  = (const float*)d_in[1];
  const float* rho = (const float*)d_in[2];
  const float* Q   = (const float*)d_in[3];
  const int* src_z = (const int*)d_in[4];
  const int* src_x = (const int*)d_in[5];
  const int* rec_x = (const int*)d_in[6];
  const int* rec_z = (const int*)d_in[7];
  float* out = (float*)d_out;
  float* ws  = (float*)d_ws;

  const size_t S = (size_t)B * NZ * NX;        // 262144 elems per field
  float* P[2]  = {ws,         ws + 4 * S};
  float* VX[2] = {ws + S,     ws + 5 * S};
  float* VZ[2] = {ws + 2 * S, ws + 6 * S};
  float* R[2]  = {ws + 3 * S, ws + 7 * S};
  float* a1 = ws + 8 * S;
  float* b2 = a1 + (size_t)NZ * NX;
  float* b3 = b2 + (size_t)NZ * NX;

  hipMemsetAsync(ws, 0, 4 * S * sizeof(float), stream);   // zero initial state
  coef_kernel<<<(NZ * NX + 255) / 256, 256, 0, stream>>>(vp, rho, Q, a1, b2, b3);

  for (int l = 0; l < NL; ++l) {
    int i = l & 1, o = i ^ 1;
    step_fused<<<NBLK, 1024, 0, stream>>>(P[i], P[o], VX[i], VX[o],
                                          VZ[i], VZ[o], R[i], R[o],
                                          a1, b2, b3, xw, src_z, src_x,
                                          rec_x, rec_z, out, l * K);
  }
}